// Round 4
// baseline (502.111 us; speedup 1.0000x reference)
//
#include <hip/hip_runtime.h>
#include <math.h>

#define EPS_AREA 1e-6f
#define EPS_BCE  1e-7f

typedef float v4f __attribute__((ext_vector_type(4)));

// ---------------------------------------------------------------------------
// Fused fast-path kernel (exact shape L=512, Lp=64, K=17, inner=3136):
//   block 0            : computes the ENTIRE loss -> loss_slot (runs ~22 us,
//                        hidden under the concurrent broadcast ~53 us)
//   blocks 1..gridDim-1: grid-stride float4 broadcast of features_poses
// Single dispatch, no atomics, no init ordering, no second launch.
// ---------------------------------------------------------------------------
template <int L, int Lp, int K, int INNER4>
__global__ __launch_bounds__(256) void fused_kernel(
    const float* __restrict__ pred_poses,     // (L,K,3) == (L, 3K) rows flat
    const float* __restrict__ target_poses,   // (Lp,K,3)
    const float* __restrict__ pred_feedbacks, // (L,)
    const float* __restrict__ ious,           // (L,Lp)
    const float* __restrict__ target_areas,   // (Lp,)
    float* __restrict__ out,
    float* __restrict__ loss_slot,
    unsigned int total4)
{
    const int tid = threadIdx.x;

    if (blockIdx.x == 0) {
        // ---- loss, whole thing in one block (4 waves) ----
        __shared__ float4 tile[32][K];   // (px, py, log(pv), log(1-pv)) per (l,k)
        __shared__ float  wsum[4];
        const int w    = tid >> 6;
        const int lane = tid & 63;

        // per-lane target row cached in registers (K unrolled -> regs)
        float tx[K], ty[K], tv[K];
        float invDen = 0.0f;
        if (lane < Lp) {
            invDen = 1.0f / (2.0f * target_areas[lane] + EPS_AREA);
            const float* t = target_poses + (size_t)lane * K * 3;
            #pragma unroll
            for (int k = 0; k < K; ++k) {
                tx[k] = t[3 * k + 0];
                ty[k] = t[3 * k + 1];
                tv[k] = t[3 * k + 2];
            }
        }

        float wacc = 0.0f;
        for (int tb = 0; tb < L / 32; ++tb) {
            __syncthreads();  // protect previous tile's readers
            for (int e = tid; e < 32 * K; e += 256) {
                const int lo = e / K;
                const int k  = e - lo * K;
                const float* p = pred_poses + ((size_t)(tb * 32 + lo) * K + k) * 3;
                float4 c;
                c.x = p[0];
                c.y = p[1];
                float pv = fminf(fmaxf(p[2], EPS_BCE), 1.0f - EPS_BCE);
                c.z = logf(pv);
                c.w = logf(1.0f - pv);
                tile[lo][k] = c;
            }
            __syncthreads();

            for (int lo = w; lo < 32; lo += 4) {   // one l per wave at a time
                const int l = tb * 32 + lo;
                float eS = 0.0f, bS = 0.0f;
                #pragma unroll
                for (int k = 0; k < K; ++k) {
                    float4 c = tile[lo][k];        // wave-uniform LDS broadcast
                    float dx = c.x - tx[k];
                    float dy = c.y - ty[k];
                    eS += __expf(-(dx * dx + dy * dy) * invDen);
                    bS += fmaf(tv[k], c.z - c.w, c.w);
                }
                float val = 0.0f;
                if (lane < Lp) {
                    float d = pred_feedbacks[l] - eS / (float)K;
                    val = ious[(size_t)l * Lp + lane] * (d * d - bS / (float)K);
                }
                #pragma unroll
                for (int off = 1; off < 64; off <<= 1)
                    val += __shfl_xor(val, off, 64);
                wacc += val;                        // all lanes hold same sum
            }
        }
        if (lane == 0) wsum[w] = wacc;
        __syncthreads();
        if (tid == 0) *loss_slot = wsum[0] + wsum[1] + wsum[2] + wsum[3];
    } else {
        // ---- broadcast: same flat float4 pattern as the 6.25 TB/s fill ----
        v4f* dst = (v4f*)out;
        const unsigned int stride = (gridDim.x - 1) * 256u;
        for (unsigned int i = (blockIdx.x - 1) * 256u + tid; i < total4;
             i += stride) {
            const unsigned int row = i / (unsigned int)INNER4;  // magic div
            const float v = pred_poses[row];
            v4f val;
            val.x = v; val.y = v; val.z = v; val.w = v;
            dst[i] = val;
        }
    }
}

// ------------------------- generic fallbacks (any shape) -------------------
__global__ __launch_bounds__(256) void broadcast_rows_kernel(
    const float* __restrict__ pred, float* __restrict__ out,
    int rows, long inner, int inner4)
{
    const int wave = threadIdx.x >> 6;
    const int lane = threadIdx.x & 63;
    const int row  = blockIdx.x * 4 + wave;
    if (row >= rows) return;
    const float v = pred[row];
    v4f val;
    val.x = v; val.y = v; val.z = v; val.w = v;
    float* rowp = out + (size_t)row * (size_t)inner;
    v4f* dst = (v4f*)rowp;
    for (int i = lane; i < inner4; i += 64) dst[i] = val;
    const int rem = (int)(inner - (long)inner4 * 4);
    if (rem && lane < rem) rowp[(size_t)inner4 * 4 + lane] = v;
}

__global__ __launch_bounds__(64) void loss_partial1_kernel(
    const float* __restrict__ pred_poses, const float* __restrict__ target_poses,
    const float* __restrict__ pred_feedbacks, const float* __restrict__ ious,
    const float* __restrict__ target_areas, float* __restrict__ partial,
    int Lp, int K)
{
    extern __shared__ float sm[];
    float* px  = sm;
    float* py  = sm + K;
    float* lpv = sm + 2 * K;
    float* l1m = sm + 3 * K;

    const int l   = blockIdx.x;
    const int tid = threadIdx.x;
    if (tid < K) {
        const float* p = pred_poses + ((size_t)l * K + tid) * 3;
        px[tid] = p[0];
        py[tid] = p[1];
        float pv = fminf(fmaxf(p[2], EPS_BCE), 1.0f - EPS_BCE);
        lpv[tid] = logf(pv);
        l1m[tid] = logf(1.0f - pv);
    }
    __syncthreads();

    float acc = 0.0f;
    for (int lp = tid; lp < Lp; lp += 64) {
        const float  invDen = 1.0f / (2.0f * target_areas[lp] + EPS_AREA);
        const float* t = target_poses + (size_t)lp * K * 3;
        float eS = 0.0f, bS = 0.0f;
        for (int k = 0; k < K; ++k) {
            float dx = px[k] - t[3 * k + 0];
            float dy = py[k] - t[3 * k + 1];
            float tvv = t[3 * k + 2];
            eS += __expf(-(dx * dx + dy * dy) * invDen);
            bS += fmaf(tvv, lpv[k] - l1m[k], l1m[k]);
        }
        float d = pred_feedbacks[l] - eS / (float)K;
        acc += ious[(size_t)l * Lp + lp] * (d * d - bS / (float)K);
    }
    for (int off = 32; off > 0; off >>= 1) acc += __shfl_down(acc, off, 64);
    if (tid == 0) partial[l] = acc;
}

__global__ __launch_bounds__(256) void loss_reduce_kernel(
    const float* __restrict__ partial, float* __restrict__ loss_out, int L)
{
    __shared__ float wsum[4];
    float s = 0.0f;
    for (int i = threadIdx.x; i < L; i += 256) s += partial[i];
    for (int off = 32; off > 0; off >>= 1) s += __shfl_down(s, off, 64);
    if ((threadIdx.x & 63) == 0) wsum[threadIdx.x >> 6] = s;
    __syncthreads();
    if (threadIdx.x == 0) *loss_out = wsum[0] + wsum[1] + wsum[2] + wsum[3];
}

extern "C" void kernel_launch(void* const* d_in, const int* in_sizes, int n_in,
                              void* d_out, int out_size, void* d_ws, size_t ws_size,
                              hipStream_t stream) {
    const float* pred_poses     = (const float*)d_in[0];  // (L,K,3)
    const float* target_poses   = (const float*)d_in[1];  // (Lp,K,3)
    const float* pred_feedbacks = (const float*)d_in[2];  // (L,)
    const float* ious           = (const float*)d_in[3];  // (L,Lp)
    const float* target_areas   = (const float*)d_in[4];  // (Lp,)
    float* out = (float*)d_out;

    const int L  = in_sizes[2];                 // 512
    const int Lp = in_sizes[4];                 // 64
    const int K  = in_sizes[0] / (3 * L);       // 17

    const long rows   = (long)L * 3 * K;                  // 26112
    const long inner  = ((long)out_size - 1) / rows;      // fd*fd = 3136
    const int  inner4 = (int)(inner / 4);                 // 784
    const int  rem    = (int)(inner - (long)inner4 * 4);  // 0

    float* loss_slot = out + ((size_t)out_size - 1);

    if (L == 512 && Lp == 64 && K == 17 && inner4 == 784 && rem == 0) {
        const unsigned int total4 = (unsigned int)(rows * 784);
        fused_kernel<512, 64, 17, 784><<<4097, 256, 0, stream>>>(
            pred_poses, target_poses, pred_feedbacks, ious, target_areas,
            out, loss_slot, total4);
    } else {
        float* partial = (float*)d_ws;  // L floats
        const size_t smem = 4 * (size_t)K * sizeof(float);
        loss_partial1_kernel<<<L, 64, smem, stream>>>(
            pred_poses, target_poses, pred_feedbacks, ious, target_areas,
            partial, Lp, K);
        broadcast_rows_kernel<<<(int)((rows + 3) / 4), 256, 0, stream>>>(
            pred_poses, out, (int)rows, inner, inner4);
        loss_reduce_kernel<<<1, 256, 0, stream>>>(partial, loss_slot, L);
    }
}

// Round 5
// 489.673 us; speedup vs baseline: 1.0254x; 1.0254x over previous
//
#include <hip/hip_runtime.h>
#include <math.h>

#define EPS_AREA 1e-6f
#define EPS_BCE  1e-7f

typedef float v4f __attribute__((ext_vector_type(4)));

// ---------------------------------------------------------------------------
// Fused fast-path kernel (exact shape L=512, Lp=64, K=17, inner=3136):
//   block 0            : entire loss -> loss_slot. ALL state in LDS/regs,
//                        NO lane-private arrays (round-4's 51-float arrays
//                        spilled to scratch at VGPR=48 -> 243 us straggler).
//   blocks 1..gridDim-1: grid-stride float4 broadcast (~60 us, BW-bound).
// Dispatch time = max(block0 ~20us, broadcast ~60us) -> broadcast-bound.
// ---------------------------------------------------------------------------
template <int L, int Lp, int K, int INNER4>
__global__ __launch_bounds__(256) void fused_kernel(
    const float* __restrict__ pred_poses,     // (L,K,3)
    const float* __restrict__ target_poses,   // (Lp,K,3)
    const float* __restrict__ pred_feedbacks, // (L,)
    const float* __restrict__ ious,           // (L,Lp)
    const float* __restrict__ target_areas,   // (Lp,)
    float* __restrict__ out,
    float* __restrict__ loss_slot,
    unsigned int total4)
{
    const int tid = threadIdx.x;

    if (blockIdx.x == 0) {
        // ---- loss, one block (4 waves), everything staged in LDS ----
        __shared__ float  txs[K][64], tys[K][64], tvs[K][64]; // targets, lane-major
        __shared__ float4 tile[32][K];  // (px,py,log pv,log1m pv) per (l,k)
        __shared__ float  wsum[4];
        const int w    = tid >> 6;
        const int lane = tid & 63;

        // stage target_poses -> LDS (lane-indexed stride-1: 2-way alias, free)
        for (int e = tid; e < Lp * K * 3; e += 256) {
            const int lp = e / (K * 3);
            const int r  = e - lp * (K * 3);
            const int k  = r / 3;
            const int c  = r - 3 * k;
            const float vv = target_poses[e];
            if (c == 0)      txs[k][lp] = vv;
            else if (c == 1) tys[k][lp] = vv;
            else             tvs[k][lp] = vv;
        }
        float invDen = 0.0f;
        if (lane < Lp) invDen = 1.0f / (2.0f * target_areas[lane] + EPS_AREA);

        const float invK = 1.0f / (float)K;
        float wacc = 0.0f;                 // per-lane accumulator over all l
        for (int tb = 0; tb < L / 32; ++tb) {
            __syncthreads();               // also covers initial target staging
            for (int e = tid; e < 32 * K; e += 256) {
                const int lo = e / K;
                const int k  = e - lo * K;
                const float* p = pred_poses + ((size_t)(tb * 32 + lo) * K + k) * 3;
                float4 c;
                c.x = p[0];
                c.y = p[1];
                float pv = fminf(fmaxf(p[2], EPS_BCE), 1.0f - EPS_BCE);
                c.z = logf(pv);
                c.w = logf(1.0f - pv);
                tile[lo][k] = c;
            }
            __syncthreads();

            for (int lo = w; lo < 32; lo += 4) {   // 8 l per wave per tile
                const int l = tb * 32 + lo;
                float eS = 0.0f, bS = 0.0f;
                #pragma unroll
                for (int k = 0; k < K; ++k) {
                    float4 c = tile[lo][k];        // wave-uniform broadcast
                    float dx = c.x - txs[k][lane];
                    float dy = c.y - tys[k][lane];
                    eS += __expf(-(dx * dx + dy * dy) * invDen);
                    bS += fmaf(tvs[k][lane], c.z - c.w, c.w);
                }
                if (lane < Lp) {
                    float d = pred_feedbacks[l] - eS * invK;
                    wacc += ious[(size_t)l * Lp + lane] * (d * d - bS * invK);
                }
            }
        }
        // single final reduce: lanes -> wave, waves -> LDS
        #pragma unroll
        for (int off = 1; off < 64; off <<= 1)
            wacc += __shfl_xor(wacc, off, 64);
        if (lane == 0) wsum[w] = wacc;
        __syncthreads();
        if (tid == 0) *loss_slot = wsum[0] + wsum[1] + wsum[2] + wsum[3];
    } else {
        // ---- broadcast: flat float4 grid-stride (the 6.2 TB/s fill pattern)
        v4f* dst = (v4f*)out;
        const unsigned int stride = (gridDim.x - 1) * 256u;
        for (unsigned int i = (blockIdx.x - 1) * 256u + tid; i < total4;
             i += stride) {
            const unsigned int row = i / (unsigned int)INNER4;  // magic div
            const float v = pred_poses[row];
            v4f val;
            val.x = v; val.y = v; val.z = v; val.w = v;
            dst[i] = val;
        }
    }
}

// ------------------------- generic fallbacks (any shape) -------------------
__global__ __launch_bounds__(256) void broadcast_rows_kernel(
    const float* __restrict__ pred, float* __restrict__ out,
    int rows, long inner, int inner4)
{
    const int wave = threadIdx.x >> 6;
    const int lane = threadIdx.x & 63;
    const int row  = blockIdx.x * 4 + wave;
    if (row >= rows) return;
    const float v = pred[row];
    v4f val;
    val.x = v; val.y = v; val.z = v; val.w = v;
    float* rowp = out + (size_t)row * (size_t)inner;
    v4f* dst = (v4f*)rowp;
    for (int i = lane; i < inner4; i += 64) dst[i] = val;
    const int rem = (int)(inner - (long)inner4 * 4);
    if (rem && lane < rem) rowp[(size_t)inner4 * 4 + lane] = v;
}

__global__ __launch_bounds__(64) void loss_partial1_kernel(
    const float* __restrict__ pred_poses, const float* __restrict__ target_poses,
    const float* __restrict__ pred_feedbacks, const float* __restrict__ ious,
    const float* __restrict__ target_areas, float* __restrict__ partial,
    int Lp, int K)
{
    extern __shared__ float sm[];
    float* px  = sm;
    float* py  = sm + K;
    float* lpv = sm + 2 * K;
    float* l1m = sm + 3 * K;

    const int l   = blockIdx.x;
    const int tid = threadIdx.x;
    if (tid < K) {
        const float* p = pred_poses + ((size_t)l * K + tid) * 3;
        px[tid] = p[0];
        py[tid] = p[1];
        float pv = fminf(fmaxf(p[2], EPS_BCE), 1.0f - EPS_BCE);
        lpv[tid] = logf(pv);
        l1m[tid] = logf(1.0f - pv);
    }
    __syncthreads();

    float acc = 0.0f;
    for (int lp = tid; lp < Lp; lp += 64) {
        const float  invDen = 1.0f / (2.0f * target_areas[lp] + EPS_AREA);
        const float* t = target_poses + (size_t)lp * K * 3;
        float eS = 0.0f, bS = 0.0f;
        for (int k = 0; k < K; ++k) {
            float dx = px[k] - t[3 * k + 0];
            float dy = py[k] - t[3 * k + 1];
            float tvv = t[3 * k + 2];
            eS += __expf(-(dx * dx + dy * dy) * invDen);
            bS += fmaf(tvv, lpv[k] - l1m[k], l1m[k]);
        }
        float d = pred_feedbacks[l] - eS / (float)K;
        acc += ious[(size_t)l * Lp + lp] * (d * d - bS / (float)K);
    }
    for (int off = 32; off > 0; off >>= 1) acc += __shfl_down(acc, off, 64);
    if (tid == 0) partial[l] = acc;
}

__global__ __launch_bounds__(256) void loss_reduce_kernel(
    const float* __restrict__ partial, float* __restrict__ loss_out, int L)
{
    __shared__ float wsum[4];
    float s = 0.0f;
    for (int i = threadIdx.x; i < L; i += 256) s += partial[i];
    for (int off = 32; off > 0; off >>= 1) s += __shfl_down(s, off, 64);
    if ((threadIdx.x & 63) == 0) wsum[threadIdx.x >> 6] = s;
    __syncthreads();
    if (threadIdx.x == 0) *loss_out = wsum[0] + wsum[1] + wsum[2] + wsum[3];
}

extern "C" void kernel_launch(void* const* d_in, const int* in_sizes, int n_in,
                              void* d_out, int out_size, void* d_ws, size_t ws_size,
                              hipStream_t stream) {
    const float* pred_poses     = (const float*)d_in[0];  // (L,K,3)
    const float* target_poses   = (const float*)d_in[1];  // (Lp,K,3)
    const float* pred_feedbacks = (const float*)d_in[2];  // (L,)
    const float* ious           = (const float*)d_in[3];  // (L,Lp)
    const float* target_areas   = (const float*)d_in[4];  // (Lp,)
    float* out = (float*)d_out;

    const int L  = in_sizes[2];                 // 512
    const int Lp = in_sizes[4];                 // 64
    const int K  = in_sizes[0] / (3 * L);       // 17

    const long rows   = (long)L * 3 * K;                  // 26112
    const long inner  = ((long)out_size - 1) / rows;      // fd*fd = 3136
    const int  inner4 = (int)(inner / 4);                 // 784
    const int  rem    = (int)(inner - (long)inner4 * 4);  // 0

    float* loss_slot = out + ((size_t)out_size - 1);

    if (L == 512 && Lp == 64 && K == 17 && inner4 == 784 && rem == 0) {
        const unsigned int total4 = (unsigned int)(rows * 784);
        fused_kernel<512, 64, 17, 784><<<4097, 256, 0, stream>>>(
            pred_poses, target_poses, pred_feedbacks, ious, target_areas,
            out, loss_slot, total4);
    } else {
        float* partial = (float*)d_ws;  // L floats
        const size_t smem = 4 * (size_t)K * sizeof(float);
        loss_partial1_kernel<<<L, 64, smem, stream>>>(
            pred_poses, target_poses, pred_feedbacks, ious, target_areas,
            partial, Lp, K);
        broadcast_rows_kernel<<<(int)((rows + 3) / 4), 256, 0, stream>>>(
            pred_poses, out, (int)rows, inner, inner4);
        loss_reduce_kernel<<<1, 256, 0, stream>>>(partial, loss_slot, L);
    }
}

// Round 6
// 337.858 us; speedup vs baseline: 1.4862x; 1.4493x over previous
//
#include <hip/hip_runtime.h>
#include <math.h>

#define EPS_AREA 1e-6f
#define EPS_BCE  1e-7f

typedef float v4f __attribute__((ext_vector_type(4)));

// ---------------------------------------------------------------------------
// Round-3 structure (measured best: 335.9 us total) restored.
// Fast path = 2 dispatches:
//   1) loss_partial kernel: partial[l] -> d_ws   (~5-8 us, quiet machine)
//   2) broadcast_flat kernel: block 0 wave 0 reduces partial -> loss_slot,
//      all blocks stream float4 stores at the fill-kernel's ~6 TB/s pattern.
// Fusion of the loss into the broadcast dispatch was tried twice (r4: 243us,
// r5: 226us): block 0's serially-exposed scattered loads starve behind the
// store firehose -> 4x straggler. Do NOT re-fuse.
// ---------------------------------------------------------------------------

template <int INNER4>
__global__ __launch_bounds__(256) void broadcast_flat_kernel(
    const float* __restrict__ pred, float* __restrict__ out,
    unsigned int total4,
    const float* __restrict__ partial, float* __restrict__ loss_out, int L)
{
    if (blockIdx.x == 0 && threadIdx.x < 64) {
        float s = 0.0f;
        for (int i = threadIdx.x; i < L; i += 64) s += partial[i];
        for (int off = 32; off > 0; off >>= 1) s += __shfl_down(s, off, 64);
        if (threadIdx.x == 0) *loss_out = s;
    }

    v4f* dst = (v4f*)out;
    const unsigned int stride = gridDim.x * blockDim.x;
    for (unsigned int i = blockIdx.x * blockDim.x + threadIdx.x; i < total4;
         i += stride) {
        const unsigned int row = i / (unsigned int)INNER4;  // magic div
        const float v = pred[row];
        v4f val;
        val.x = v; val.y = v; val.z = v; val.w = v;
        dst[i] = val;
    }
}

// Loss stage 1: LPB l's per block, 256 threads = 4 waves. Wave w handles
// k = w, w+4, ...; lane = lp. LDS combine, wave 0 finishes. No atomics.
template <int LPB>
__global__ __launch_bounds__(256) void loss_partial4_kernel(
    const float* __restrict__ pred_poses,     // (L,K,3)
    const float* __restrict__ target_poses,   // (Lp,K,3)
    const float* __restrict__ pred_feedbacks, // (L,)
    const float* __restrict__ ious,           // (L,Lp)
    const float* __restrict__ target_areas,   // (Lp,)
    float* __restrict__ partial,              // (L,)
    int Lp, int K)
{
    extern __shared__ float sm[];  // px[K] py[K] lpv[K] l1m[K] red[512]
    float* px  = sm;
    float* py  = sm + K;
    float* lpv = sm + 2 * K;
    float* l1m = sm + 3 * K;
    float* red = sm + 4 * K;       // 512 floats: eSum[256], bSum[256]

    const int tid  = threadIdx.x;
    const int w    = tid >> 6;
    const int lane = tid & 63;

    float invDen = 0.0f;
    if (lane < Lp) invDen = 1.0f / (2.0f * target_areas[lane] + EPS_AREA);
    const float* t = target_poses + (size_t)lane * K * 3;  // valid if lane<Lp

    for (int li = 0; li < LPB; ++li) {
        const int l = blockIdx.x * LPB + li;

        if (li) __syncthreads();   // protect previous iteration's red[] reads
        if (tid < K) {
            const float* p = pred_poses + ((size_t)l * K + tid) * 3;
            px[tid] = p[0];
            py[tid] = p[1];
            float pv = fminf(fmaxf(p[2], EPS_BCE), 1.0f - EPS_BCE);
            lpv[tid] = logf(pv);
            l1m[tid] = logf(1.0f - pv);
        }
        __syncthreads();

        float eS = 0.0f, bS = 0.0f;
        if (lane < Lp) {
            for (int k = w; k < K; k += 4) {
                float tx = t[3 * k + 0];
                float ty = t[3 * k + 1];
                float tv = t[3 * k + 2];
                float dx = px[k] - tx;
                float dy = py[k] - ty;
                eS += __expf(-(dx * dx + dy * dy) * invDen);
                bS += fmaf(tv, lpv[k] - l1m[k], l1m[k]);
            }
        }
        red[tid]       = eS;
        red[256 + tid] = bS;
        __syncthreads();

        if (w == 0) {
            float eSum = red[lane] + red[64 + lane] + red[128 + lane] + red[192 + lane];
            float bSum = red[256 + lane] + red[320 + lane] + red[384 + lane] + red[448 + lane];
            float val = 0.0f;
            if (lane < Lp) {
                float tf = eSum / (float)K;
                float d  = pred_feedbacks[l] - tf;
                val = ious[(size_t)l * Lp + lane] * (d * d - bSum / (float)K);
            }
            for (int off = 32; off > 0; off >>= 1) val += __shfl_down(val, off, 64);
            if (lane == 0) partial[l] = val;
        }
    }
}

// ------------------------- generic fallbacks (any shape) -------------------
__global__ __launch_bounds__(256) void broadcast_rows_kernel(
    const float* __restrict__ pred, float* __restrict__ out,
    int rows, long inner, int inner4)
{
    const int wave = threadIdx.x >> 6;
    const int lane = threadIdx.x & 63;
    const int row  = blockIdx.x * 4 + wave;
    if (row >= rows) return;
    const float v = pred[row];
    v4f val;
    val.x = v; val.y = v; val.z = v; val.w = v;
    float* rowp = out + (size_t)row * (size_t)inner;
    v4f* dst = (v4f*)rowp;
    for (int i = lane; i < inner4; i += 64) dst[i] = val;
    const int rem = (int)(inner - (long)inner4 * 4);
    if (rem && lane < rem) rowp[(size_t)inner4 * 4 + lane] = v;
}

__global__ __launch_bounds__(64) void loss_partial1_kernel(
    const float* __restrict__ pred_poses, const float* __restrict__ target_poses,
    const float* __restrict__ pred_feedbacks, const float* __restrict__ ious,
    const float* __restrict__ target_areas, float* __restrict__ partial,
    int Lp, int K)
{
    extern __shared__ float sm[];
    float* px  = sm;
    float* py  = sm + K;
    float* lpv = sm + 2 * K;
    float* l1m = sm + 3 * K;

    const int l   = blockIdx.x;
    const int tid = threadIdx.x;
    if (tid < K) {
        const float* p = pred_poses + ((size_t)l * K + tid) * 3;
        px[tid] = p[0];
        py[tid] = p[1];
        float pv = fminf(fmaxf(p[2], EPS_BCE), 1.0f - EPS_BCE);
        lpv[tid] = logf(pv);
        l1m[tid] = logf(1.0f - pv);
    }
    __syncthreads();

    float acc = 0.0f;
    for (int lp = tid; lp < Lp; lp += 64) {
        const float  invDen = 1.0f / (2.0f * target_areas[lp] + EPS_AREA);
        const float* t = target_poses + (size_t)lp * K * 3;
        float eS = 0.0f, bS = 0.0f;
        for (int k = 0; k < K; ++k) {
            float dx = px[k] - t[3 * k + 0];
            float dy = py[k] - t[3 * k + 1];
            float tvv = t[3 * k + 2];
            eS += __expf(-(dx * dx + dy * dy) * invDen);
            bS += fmaf(tvv, lpv[k] - l1m[k], l1m[k]);
        }
        float d = pred_feedbacks[l] - eS / (float)K;
        acc += ious[(size_t)l * Lp + lp] * (d * d - bS / (float)K);
    }
    for (int off = 32; off > 0; off >>= 1) acc += __shfl_down(acc, off, 64);
    if (tid == 0) partial[l] = acc;
}

__global__ __launch_bounds__(256) void loss_reduce_kernel(
    const float* __restrict__ partial, float* __restrict__ loss_out, int L)
{
    __shared__ float wsum[4];
    float s = 0.0f;
    for (int i = threadIdx.x; i < L; i += 256) s += partial[i];
    for (int off = 32; off > 0; off >>= 1) s += __shfl_down(s, off, 64);
    if ((threadIdx.x & 63) == 0) wsum[threadIdx.x >> 6] = s;
    __syncthreads();
    if (threadIdx.x == 0) *loss_out = wsum[0] + wsum[1] + wsum[2] + wsum[3];
}

extern "C" void kernel_launch(void* const* d_in, const int* in_sizes, int n_in,
                              void* d_out, int out_size, void* d_ws, size_t ws_size,
                              hipStream_t stream) {
    const float* pred_poses     = (const float*)d_in[0];  // (L,K,3)
    const float* target_poses   = (const float*)d_in[1];  // (Lp,K,3)
    const float* pred_feedbacks = (const float*)d_in[2];  // (L,)
    const float* ious           = (const float*)d_in[3];  // (L,Lp)
    const float* target_areas   = (const float*)d_in[4];  // (Lp,)
    float* out = (float*)d_out;

    const int L  = in_sizes[2];                 // 512
    const int Lp = in_sizes[4];                 // 64
    const int K  = in_sizes[0] / (3 * L);       // 17

    const long rows   = (long)L * 3 * K;                  // 26112
    const long inner  = ((long)out_size - 1) / rows;      // fd*fd = 3136
    const int  inner4 = (int)(inner / 4);                 // 784
    const int  rem    = (int)(inner - (long)inner4 * 4);  // 0

    float* loss_slot = out + ((size_t)out_size - 1);
    float* partial   = (float*)d_ws;                      // L floats

    if (L == 512 && Lp <= 64 && K == 17 && inner4 == 784 && rem == 0) {
        const size_t smem = (4 * (size_t)K + 512) * sizeof(float);
        loss_partial4_kernel<2><<<L / 2, 256, smem, stream>>>(
            pred_poses, target_poses, pred_feedbacks, ious, target_areas,
            partial, Lp, K);
        const unsigned int total4 = (unsigned int)(rows * 784);
        broadcast_flat_kernel<784><<<4096, 256, 0, stream>>>(
            pred_poses, out, total4, partial, loss_slot, L);
    } else {
        const size_t smem = 4 * (size_t)K * sizeof(float);
        loss_partial1_kernel<<<L, 64, smem, stream>>>(
            pred_poses, target_poses, pred_feedbacks, ious, target_areas,
            partial, Lp, K);
        broadcast_rows_kernel<<<(int)((rows + 3) / 4), 256, 0, stream>>>(
            pred_poses, out, (int)rows, inner, inner4);
        loss_reduce_kernel<<<1, 256, 0, stream>>>(partial, loss_slot, L);
    }
}